// Round 8
// baseline (38.410 us; speedup 1.0000x reference)
//
#include <hip/hip_runtime.h>

constexpr int NQ = 7;
constexpr int NL = 4;
constexpr int NG = NL * NQ;   // 28
constexpr int NCLS = 22;

// ---------------- cross-lane primitives ----------------
// masks 1,2 -> DPP quad_perm (proven R1/R4/R6/R7)
// mask 8    -> DPP ROW_ROR:8  ((i+8)%16 == i^8 within 16-row; same builtin
//              mechanism as quad_perm — R2's failure was the inline-asm
//              coalescing bug, fully diagnosed in R3/R5 post-mortems)
// mask 16   -> __builtin_amdgcn_permlane16_swap (gfx950 VALU; SSA-safe builtin,
//              direction-immune use: both outputs {[lo,lo],[hi,hi]} as a set,
//              so partner = (r0+r1)-v, sum = r0+r1 under either role reading)
// mask 4    -> ds_swizzle xor4 (only remaining DS-pipe user)
// NO inline asm anywhere (R2/R3/R5 lesson).

template<int CTRL>
__device__ __forceinline__ float fdpp(float v) {
    return __int_as_float(__builtin_amdgcn_mov_dpp(__float_as_int(v), CTRL, 0xF, 0xF, true));
}
template<int OFF>
__device__ __forceinline__ float fswz(float v) {
    return __int_as_float(__builtin_amdgcn_ds_swizzle(__float_as_int(v), OFF));
}

#if __has_builtin(__builtin_amdgcn_permlane16_swap)
__device__ __forceinline__ float xor16p(float v) {   // partner across lane^16
    auto r = __builtin_amdgcn_permlane16_swap(__float_as_uint(v), __float_as_uint(v), false, false);
    return (__uint_as_float(r[0]) + __uint_as_float(r[1])) - v;
}
__device__ __forceinline__ float sum16p(float v) {   // v + partner
    auto r = __builtin_amdgcn_permlane16_swap(__float_as_uint(v), __float_as_uint(v), false, false);
    return __uint_as_float(r[0]) + __uint_as_float(r[1]);
}
#else
__device__ __forceinline__ float xor16p(float v) { return fswz<0x401F>(v); }
__device__ __forceinline__ float sum16p(float v) { return v + fswz<0x401F>(v); }
#endif

template<int M>
__device__ __forceinline__ float xorl(float v) {
    if      constexpr (M == 1)  return fdpp<0xB1>(v);    // quad_perm [1,0,3,2]
    else if constexpr (M == 2)  return fdpp<0x4E>(v);    // quad_perm [2,3,0,1]
    else if constexpr (M == 4)  return fswz<0x101F>(v);  // ds_swizzle xor4
    else if constexpr (M == 8)  return fdpp<0x128>(v);   // ROW_ROR:8 == xor8
    else                        return xor16p(v);        // permlane16_swap
}

// ---------------- fused gate build: U' = U_rot @ RX(c,s) ----------------
// u[8] = {u00r,u00i,u01r,u01i,u10r,u10i,u11r,u11i} (LDS broadcast read)
__device__ __forceinline__ void fuse(const float* __restrict__ u, float c, float s,
                                     float4& A, float4& B) {
    A.x = fmaf(c, u[0],  s * u[3]);  A.y = fmaf(c, u[1], -s * u[2]);
    A.z = fmaf(c, u[2],  s * u[1]);  A.w = fmaf(c, u[3], -s * u[0]);
    B.x = fmaf(c, u[4],  s * u[7]);  B.y = fmaf(c, u[5], -s * u[6]);
    B.z = fmaf(c, u[6],  s * u[5]);  B.w = fmaf(c, u[7], -s * u[4]);
}

// 2x2 gate on a lane-bit qubit (pair across lane mask M), applied to 4 amps
template<int M>
__device__ __forceinline__ void gateL(int lane, float4 A, float4 B,
                                      float ar[4], float ai[4]) {
    const bool hi = (lane & M) != 0;
    const float avr = hi ? B.z : A.x, avi = hi ? B.w : A.y;   // diag coeff
    const float awr = hi ? B.x : A.z, awi = hi ? B.y : A.w;   // off-diag coeff
    #pragma unroll
    for (int k = 0; k < 4; ++k) {
        const float wr = xorl<M>(ar[k]), wi = xorl<M>(ai[k]);
        const float nr = avr*ar[k] - avi*ai[k] + awr*wr - awi*wi;
        const float ni = avr*ai[k] + avi*ar[k] + awr*wi + awi*wr;
        ar[k] = nr; ai[k] = ni;
    }
}

// full 2x2 on a register pair (v = row0 amp, w = row1 amp)
__device__ __forceinline__ void gate2(float4 A, float4 B,
                                      float& vr, float& vi, float& wr, float& wi) {
    const float n0r = A.x*vr - A.y*vi + A.z*wr - A.w*wi;
    const float n0i = A.x*vi + A.y*vr + A.z*wi + A.w*wr;
    const float n1r = B.x*vr - B.y*vi + B.z*wr - B.w*wi;
    const float n1i = B.x*vi + B.y*vr + B.z*wi + B.w*wr;
    vr = n0r; vi = n0i; wr = n1r; wi = n1i;
}

// CNOT with lane-bit target MT, lane-bit control MC
template<int MT, int MC>
__device__ __forceinline__ void cnotLT(int lane, float ar[4], float ai[4]) {
    const bool c = (lane & MC) != 0;
    #pragma unroll
    for (int k = 0; k < 4; ++k) {
        const float wr = xorl<MT>(ar[k]), wi = xorl<MT>(ai[k]);
        ar[k] = c ? wr : ar[k];
        ai[k] = c ? wi : ai[k];
    }
}

// ---------------- main kernel: TWO batch elements per wave, single launch ----------------
// element = lane>>5; within-half lane w = lane&31; local amp k = 0..3.
// amp index a = (w<<2)|k, bits a6..a0 = w4 w3 w2 w1 w0 k1 k0.
// qubit q <-> amp bit (6-q):  q0->w4(m16) q1->w3(m8) q2->w2(m4) q3->w1(m2)
//                             q4->w0(m1)  q5->k1(local) q6->k0(local)
__global__ __launch_bounds__(256) void reupload_kernel(
    const float* __restrict__ x,       // (B,7)
    const float* __restrict__ wts,     // (4,7,3)
    const float* __restrict__ fc1_w,   // (32,7)
    const float* __restrict__ fc1_b,   // (32,)
    const float* __restrict__ fc2_w,   // (22,32)
    const float* __restrict__ fc2_b,   // (22,)
    float* __restrict__ out,           // (B,22)
    int B)
{
    // --- per-block: 28 batch-independent Rot matrices -> LDS (R1-proven) ---
    __shared__ __align__(16) float rotU[NG * 8];
    {
        const int tid = threadIdx.x;
        if (tid < NG) {
            float phi = wts[tid*3+0], th = wts[tid*3+1], om = wts[tid*3+2];
            float ct = __cosf(0.5f*th), st = __sinf(0.5f*th);
            float ap = 0.5f*(phi+om),  am = 0.5f*(phi-om);
            float cp = __cosf(ap), sp = __sinf(ap);
            float cm = __cosf(am), sm = __sinf(am);
            float* u = &rotU[tid*8];
            u[0] =  cp*ct; u[1] = -sp*ct;   // u00 = ep*ct        (ep = cp - i sp)
            u[2] = -cm*st; u[3] = -sm*st;   // u01 = -conj(em)*st (em = cm - i sm)
            u[4] =  cm*st; u[5] = -sm*st;   // u10 = em*st
            u[6] =  cp*ct; u[7] =  sp*ct;   // u11 = conj(ep)*ct
        }
    }
    __syncthreads();

    const int lane = threadIdx.x & 63;
    const int wl   = threadIdx.x & 31;          // within-half lane
    const int grp  = threadIdx.x >> 5;          // 32-group id in block (0..7)
    const int b    = blockIdx.x * 8 + grp;      // one element per 32-group
    if (b >= B) return;

    float c[NQ], s[NQ];
    #pragma unroll
    for (int q = 0; q < NQ; ++q) {
        float h = 0.5f * x[b*NQ + q];
        c[q] = __cosf(h); s[q] = __sinf(h);
    }

    // |0..0>: amp 0 lives at w=0,k=0
    float ar[4], ai[4];
    #pragma unroll
    for (int k = 0; k < 4; ++k) { ar[k] = 0.f; ai[k] = 0.f; }
    ar[0] = (wl == 0) ? 1.f : 0.f;

    #pragma unroll
    for (int l = 0; l < NL; ++l) {
        const float* rl = &rotU[l * (NQ * 8)];
        float4 A, Bq;
        // fused Rot·RX per qubit (distinct-qubit gates commute; Rot∘RX order kept)
        fuse(rl +  0, c[0], s[0], A, Bq); gateL<16>(lane, A, Bq, ar, ai);  // q0
        fuse(rl +  8, c[1], s[1], A, Bq); gateL< 8>(lane, A, Bq, ar, ai);  // q1
        fuse(rl + 16, c[2], s[2], A, Bq); gateL< 4>(lane, A, Bq, ar, ai);  // q2
        fuse(rl + 24, c[3], s[3], A, Bq); gateL< 2>(lane, A, Bq, ar, ai);  // q3
        fuse(rl + 32, c[4], s[4], A, Bq); gateL< 1>(lane, A, Bq, ar, ai);  // q4
        fuse(rl + 40, c[5], s[5], A, Bq);                                  // q5: k1
        gate2(A, Bq, ar[0], ai[0], ar[2], ai[2]);
        gate2(A, Bq, ar[1], ai[1], ar[3], ai[3]);
        fuse(rl + 48, c[6], s[6], A, Bq);                                  // q6: k0
        gate2(A, Bq, ar[0], ai[0], ar[1], ai[1]);
        gate2(A, Bq, ar[2], ai[2], ar[3], ai[3]);

        // CNOT ring CNOT(q, q+1 mod 7), reference order q=0..6
        cnotLT<8,16>(lane, ar, ai);   // (0,1): ctrl w4, tgt w3
        cnotLT<4, 8>(lane, ar, ai);   // (1,2)
        cnotLT<2, 4>(lane, ar, ai);   // (2,3)
        cnotLT<1, 2>(lane, ar, ai);   // (3,4)
        {   // (4,5): ctrl w0 (lane&1), tgt k1 -> cond swap (0<->2),(1<->3)
            const bool cc = (lane & 1) != 0;
            float t;
            t = ar[0]; ar[0] = cc ? ar[2] : ar[0]; ar[2] = cc ? t : ar[2];
            t = ai[0]; ai[0] = cc ? ai[2] : ai[0]; ai[2] = cc ? t : ai[2];
            t = ar[1]; ar[1] = cc ? ar[3] : ar[1]; ar[3] = cc ? t : ar[3];
            t = ai[1]; ai[1] = cc ? ai[3] : ai[1]; ai[3] = cc ? t : ai[3];
        }
        {   // (5,6): ctrl k1, tgt k0 -> unconditional A2<->A3 (free reg rename)
            float t;
            t = ar[2]; ar[2] = ar[3]; ar[3] = t;
            t = ai[2]; ai[2] = ai[3]; ai[3] = t;
        }
        {   // (6,0): ctrl k0, tgt w4 -> amps k=1,3 swap across mask16 (uncond)
            ar[1] = xor16p(ar[1]); ai[1] = xor16p(ai[1]);
            ar[3] = xor16p(ar[3]); ai[3] = xor16p(ai[3]);
        }
    }

    // ---------- <Z_j> ----------
    float p[4];
    #pragma unroll
    for (int k = 0; k < 4; ++k) p[k] = ar[k]*ar[k] + ai[k]*ai[k];
    const float t01 = p[0] + p[1], t23 = p[2] + p[3];
    const float t = t01 + t23;
    float z[NQ];
    z[0] = (lane & 16) ? -t : t;
    z[1] = (lane &  8) ? -t : t;
    z[2] = (lane &  4) ? -t : t;
    z[3] = (lane &  2) ? -t : t;
    z[4] = (lane &  1) ? -t : t;
    z[5] = t01 - t23;                         // sign by k1
    z[6] = (p[0] - p[1]) + (p[2] - p[3]);     // sign by k0
    #pragma unroll
    for (int j = 0; j < NQ; ++j) {
        float v = z[j];
        v += xorl<1>(v);
        v += xorl<2>(v);
        v += xorl<4>(v);
        v += xorl<8>(v);
        v = sum16p(v);
        z[j] = v;   // full per-element sum in every lane of the half
    }

    // ---------- MLP 7 -> 32(relu) -> 22, per 32-lane half ----------
    __shared__ __align__(16) float hbuf[8][32];
    float acc1 = fc1_b[wl];
    #pragma unroll
    for (int j = 0; j < NQ; ++j) acc1 = fmaf(z[j], fc1_w[wl*NQ + j], acc1);
    hbuf[grp][wl] = fmaxf(acc1, 0.f);
    __builtin_amdgcn_wave_barrier();
    asm volatile("s_waitcnt lgkmcnt(0)" ::: "memory");
    __builtin_amdgcn_sched_barrier(0);

    float hv[32];
    #pragma unroll
    for (int i = 0; i < 8; ++i) {   // broadcast reads within each half
        float4 v4 = *reinterpret_cast<const float4*>(&hbuf[grp][i*4]);
        hv[i*4+0] = v4.x; hv[i*4+1] = v4.y; hv[i*4+2] = v4.z; hv[i*4+3] = v4.w;
    }
    const int k = (wl < NCLS) ? wl : 0;
    float acc2 = fc2_b[k];
    const float4* w4 = reinterpret_cast<const float4*>(fc2_w + k*32);
    #pragma unroll
    for (int i = 0; i < 8; ++i) {
        float4 wv = w4[i];
        acc2 = fmaf(hv[i*4+0], wv.x, acc2);
        acc2 = fmaf(hv[i*4+1], wv.y, acc2);
        acc2 = fmaf(hv[i*4+2], wv.z, acc2);
        acc2 = fmaf(hv[i*4+3], wv.w, acc2);
    }
    if (wl < NCLS) out[b*NCLS + wl] = acc2;
}

extern "C" void kernel_launch(void* const* d_in, const int* in_sizes, int n_in,
                              void* d_out, int out_size, void* d_ws, size_t ws_size,
                              hipStream_t stream) {
    const float* x     = (const float*)d_in[0];
    const float* wts   = (const float*)d_in[1];
    const float* fc1_w = (const float*)d_in[2];
    const float* fc1_b = (const float*)d_in[3];
    const float* fc2_w = (const float*)d_in[4];
    const float* fc2_b = (const float*)d_in[5];
    float* out = (float*)d_out;

    const int B = in_sizes[0] / NQ;            // 16384
    const int grid = (B + 7) / 8;              // 8 elements per 256-thread block
    reupload_kernel<<<grid, 256, 0, stream>>>(x, wts, fc1_w, fc1_b, fc2_w, fc2_b, out, B);
}

// Round 9
// 30.016 us; speedup vs baseline: 1.2797x; 1.2797x over previous
//
#include <hip/hip_runtime.h>

constexpr int NQ = 7;
constexpr int NL = 4;
constexpr int NG = NL * NQ;   // 28
constexpr int NCLS = 22;
constexpr int EPB = 8;        // batch elements per 256-thread block (one per 32-lane half)

// ---------------- cross-lane primitives: R7-PROVEN SET ----------------
// masks 1,2 -> DPP quad_perm; masks 4,8,16 -> ds_swizzle XOR.
// (R8 lesson: at VALUBusy~70%, DS-pipe shuffles beat VALU permlanes — keep DS.)
template<int CTRL>
__device__ __forceinline__ float fdpp(float v) {
    return __int_as_float(__builtin_amdgcn_mov_dpp(__float_as_int(v), CTRL, 0xF, 0xF, true));
}
template<int OFF>
__device__ __forceinline__ float fswz(float v) {
    return __int_as_float(__builtin_amdgcn_ds_swizzle(__float_as_int(v), OFF));
}
template<int M>
__device__ __forceinline__ float xorl(float v) {
    if      constexpr (M == 1)  return fdpp<0xB1>(v);    // quad_perm [1,0,3,2]
    else if constexpr (M == 2)  return fdpp<0x4E>(v);    // quad_perm [2,3,0,1]
    else if constexpr (M == 4)  return fswz<0x101F>(v);  // xor4
    else if constexpr (M == 8)  return fswz<0x201F>(v);  // xor8
    else                        return fswz<0x401F>(v);  // xor16
}

// ---------------- fused gate build: U' = U_rot @ RX(c,s) ----------------
__device__ __forceinline__ void fuse(const float* __restrict__ u, float c, float s,
                                     float4& A, float4& B) {
    A.x = fmaf(c, u[0],  s * u[3]);  A.y = fmaf(c, u[1], -s * u[2]);
    A.z = fmaf(c, u[2],  s * u[1]);  A.w = fmaf(c, u[3], -s * u[0]);
    B.x = fmaf(c, u[4],  s * u[7]);  B.y = fmaf(c, u[5], -s * u[6]);
    B.z = fmaf(c, u[6],  s * u[5]);  B.w = fmaf(c, u[7], -s * u[4]);
}

// 2x2 gate on a lane-bit qubit (pair across lane mask M), applied to 4 amps
template<int M>
__device__ __forceinline__ void gateL(int lane, float4 A, float4 B,
                                      float ar[4], float ai[4]) {
    const bool hi = (lane & M) != 0;
    const float avr = hi ? B.z : A.x, avi = hi ? B.w : A.y;   // diag coeff
    const float awr = hi ? B.x : A.z, awi = hi ? B.y : A.w;   // off-diag coeff
    #pragma unroll
    for (int k = 0; k < 4; ++k) {
        const float wr = xorl<M>(ar[k]), wi = xorl<M>(ai[k]);
        const float nr = avr*ar[k] - avi*ai[k] + awr*wr - awi*wi;
        const float ni = avr*ai[k] + avi*ar[k] + awr*wi + awi*wr;
        ar[k] = nr; ai[k] = ni;
    }
}

// full 2x2 on a register pair (v = row0 amp, w = row1 amp)
__device__ __forceinline__ void gate2(float4 A, float4 B,
                                      float& vr, float& vi, float& wr, float& wi) {
    const float n0r = A.x*vr - A.y*vi + A.z*wr - A.w*wi;
    const float n0i = A.x*vi + A.y*vr + A.z*wi + A.w*wr;
    const float n1r = B.x*vr - B.y*vi + B.z*wr - B.w*wi;
    const float n1i = B.x*vi + B.y*vr + B.z*wi + B.w*wr;
    vr = n0r; vi = n0i; wr = n1r; wi = n1i;
}

// CNOT with lane-bit target MT, lane-bit control MC
template<int MT, int MC>
__device__ __forceinline__ void cnotLT(int lane, float ar[4], float ai[4]) {
    const bool c = (lane & MC) != 0;
    #pragma unroll
    for (int k = 0; k < 4; ++k) {
        const float wr = xorl<MT>(ar[k]), wi = xorl<MT>(ai[k]);
        ar[k] = c ? wr : ar[k];
        ai[k] = c ? wi : ai[k];
    }
}

// ---------------- main kernel ----------------
// element = half-wave: grp = tid>>5 (0..7); within-half lane wl = lane&31.
// amp index a = (wl<<2)|k, bits a6..a0 = w4 w3 w2 w1 w0 k1 k0.
// qubit q <-> amp bit (6-q):  q0->w4(m16) q1->w3(m8) q2->w2(m4) q3->w1(m2)
//                             q4->w0(m1)  q5->k1(local) q6->k0(local)
// Block preamble de-replicates gate-matrix construction (R9): 224 threads build
// the 28x8 fused matrices once into LDS; main loop reads them as float4 pairs.
__global__ __launch_bounds__(256) void reupload_kernel(
    const float* __restrict__ x,       // (B,7)
    const float* __restrict__ wts,     // (4,7,3)
    const float* __restrict__ fc1_w,   // (32,7)
    const float* __restrict__ fc1_b,   // (32,)
    const float* __restrict__ fc2_w,   // (22,32)
    const float* __restrict__ fc2_b,   // (22,)
    float* __restrict__ out,           // (B,22)
    int B)
{
    __shared__ __align__(16) float rotU[NG * 8];        // 28 Rot matrices
    __shared__ float2 csb[EPB * NQ];                    // per-element RX (c,s)
    __shared__ __align__(16) float fU[NG * EPB * 8];    // fused matrices, 7 KiB
    __shared__ __align__(16) float hbuf[EPB][32];

    const int tid = threadIdx.x;
    // --- phase 0: c,s on wave 0 (56 thr) ∥ Rot matrices on wave 1 (28 thr) ---
    if (tid < EPB * NQ) {
        const int e = tid / NQ, q = tid % NQ;
        const int bb = blockIdx.x * EPB + e;
        const float xv = (bb < B) ? x[bb*NQ + q] : 0.f;
        const float h = 0.5f * xv;
        csb[tid] = make_float2(__cosf(h), __sinf(h));
    } else if (tid >= 64 && tid < 64 + NG) {
        const int g = tid - 64;
        float phi = wts[g*3+0], th = wts[g*3+1], om = wts[g*3+2];
        float ct = __cosf(0.5f*th), st = __sinf(0.5f*th);
        float ap = 0.5f*(phi+om),  am = 0.5f*(phi-om);
        float cp = __cosf(ap), sp = __sinf(ap);
        float cm = __cosf(am), sm = __sinf(am);
        float* u = &rotU[g*8];
        u[0] =  cp*ct; u[1] = -sp*ct;   // u00 = ep*ct        (ep = cp - i sp)
        u[2] = -cm*st; u[3] = -sm*st;   // u01 = -conj(em)*st (em = cm - i sm)
        u[4] =  cm*st; u[5] = -sm*st;   // u10 = em*st
        u[6] =  cp*ct; u[7] =  sp*ct;   // u11 = conj(ep)*ct
    }
    __syncthreads();
    // --- phase 1: 224 threads build one fused matrix each ---
    if (tid < NG * EPB) {
        const int g = tid >> 3, e = tid & 7;
        const int q = g % NQ;
        const float2 cs = csb[e*NQ + q];
        float4 A, Bq;
        fuse(&rotU[g*8], cs.x, cs.y, A, Bq);
        float4* dst = reinterpret_cast<float4*>(&fU[(g*EPB + e)*8]);
        dst[0] = A; dst[1] = Bq;
    }
    __syncthreads();

    const int lane = threadIdx.x & 63;
    const int wl   = threadIdx.x & 31;          // within-half lane
    const int grp  = threadIdx.x >> 5;          // half-wave id (0..7)
    const int b    = blockIdx.x * EPB + grp;
    if (b >= B) return;

    // |0..0>: amp 0 lives at wl=0,k=0
    float ar[4], ai[4];
    #pragma unroll
    for (int k = 0; k < 4; ++k) { ar[k] = 0.f; ai[k] = 0.f; }
    ar[0] = (wl == 0) ? 1.f : 0.f;

    #pragma unroll
    for (int l = 0; l < NL; ++l) {
        float4 A, Bq;
        #define LOADU(q) { const float4* up = reinterpret_cast<const float4*>( \
            &fU[((l*NQ + (q))*EPB + grp)*8]); A = up[0]; Bq = up[1]; }
        LOADU(0); gateL<16>(lane, A, Bq, ar, ai);
        LOADU(1); gateL< 8>(lane, A, Bq, ar, ai);
        LOADU(2); gateL< 4>(lane, A, Bq, ar, ai);
        LOADU(3); gateL< 2>(lane, A, Bq, ar, ai);
        LOADU(4); gateL< 1>(lane, A, Bq, ar, ai);
        LOADU(5);                                   // q5: local k1
        gate2(A, Bq, ar[0], ai[0], ar[2], ai[2]);
        gate2(A, Bq, ar[1], ai[1], ar[3], ai[3]);
        LOADU(6);                                   // q6: local k0
        gate2(A, Bq, ar[0], ai[0], ar[1], ai[1]);
        gate2(A, Bq, ar[2], ai[2], ar[3], ai[3]);
        #undef LOADU

        // CNOT ring CNOT(q, q+1 mod 7), reference order q=0..6
        cnotLT<8,16>(lane, ar, ai);   // (0,1): ctrl w4, tgt w3
        cnotLT<4, 8>(lane, ar, ai);   // (1,2)
        cnotLT<2, 4>(lane, ar, ai);   // (2,3)
        cnotLT<1, 2>(lane, ar, ai);   // (3,4)
        {   // (4,5): ctrl w0 (lane&1), tgt k1 -> cond swap (0<->2),(1<->3)
            const bool cc = (lane & 1) != 0;
            float t;
            t = ar[0]; ar[0] = cc ? ar[2] : ar[0]; ar[2] = cc ? t : ar[2];
            t = ai[0]; ai[0] = cc ? ai[2] : ai[0]; ai[2] = cc ? t : ai[2];
            t = ar[1]; ar[1] = cc ? ar[3] : ar[1]; ar[3] = cc ? t : ar[3];
            t = ai[1]; ai[1] = cc ? ai[3] : ai[1]; ai[3] = cc ? t : ai[3];
        }
        {   // (5,6): ctrl k1, tgt k0 -> unconditional A2<->A3 (free reg rename)
            float t;
            t = ar[2]; ar[2] = ar[3]; ar[3] = t;
            t = ai[2]; ai[2] = ai[3]; ai[3] = t;
        }
        {   // (6,0): ctrl k0, tgt w4 -> amps k=1,3 swap across mask16 (uncond)
            ar[1] = xorl<16>(ar[1]); ai[1] = xorl<16>(ai[1]);
            ar[3] = xorl<16>(ar[3]); ai[3] = xorl<16>(ai[3]);
        }
    }

    // ---------- <Z_j> ----------
    float p[4];
    #pragma unroll
    for (int k = 0; k < 4; ++k) p[k] = ar[k]*ar[k] + ai[k]*ai[k];
    const float t01 = p[0] + p[1], t23 = p[2] + p[3];
    const float t = t01 + t23;
    float z[NQ];
    z[0] = (lane & 16) ? -t : t;
    z[1] = (lane &  8) ? -t : t;
    z[2] = (lane &  4) ? -t : t;
    z[3] = (lane &  2) ? -t : t;
    z[4] = (lane &  1) ? -t : t;
    z[5] = t01 - t23;                         // sign by k1
    z[6] = (p[0] - p[1]) + (p[2] - p[3]);     // sign by k0
    #pragma unroll
    for (int j = 0; j < NQ; ++j) {
        float v = z[j];
        v += xorl<1>(v);
        v += xorl<2>(v);
        v += xorl<4>(v);
        v += xorl<8>(v);
        v += xorl<16>(v);
        z[j] = v;   // full per-element sum in every lane of the half
    }

    // ---------- MLP 7 -> 32(relu) -> 22, per 32-lane half ----------
    float acc1 = fc1_b[wl];
    #pragma unroll
    for (int j = 0; j < NQ; ++j) acc1 = fmaf(z[j], fc1_w[wl*NQ + j], acc1);
    hbuf[grp][wl] = fmaxf(acc1, 0.f);
    __builtin_amdgcn_wave_barrier();
    asm volatile("s_waitcnt lgkmcnt(0)" ::: "memory");
    __builtin_amdgcn_sched_barrier(0);

    float hv[32];
    #pragma unroll
    for (int i = 0; i < 8; ++i) {   // broadcast reads within each half
        float4 v4 = *reinterpret_cast<const float4*>(&hbuf[grp][i*4]);
        hv[i*4+0] = v4.x; hv[i*4+1] = v4.y; hv[i*4+2] = v4.z; hv[i*4+3] = v4.w;
    }
    const int k = (wl < NCLS) ? wl : 0;
    float acc2 = fc2_b[k];
    const float4* w4 = reinterpret_cast<const float4*>(fc2_w + k*32);
    #pragma unroll
    for (int i = 0; i < 8; ++i) {
        float4 wv = w4[i];
        acc2 = fmaf(hv[i*4+0], wv.x, acc2);
        acc2 = fmaf(hv[i*4+1], wv.y, acc2);
        acc2 = fmaf(hv[i*4+2], wv.z, acc2);
        acc2 = fmaf(hv[i*4+3], wv.w, acc2);
    }
    if (wl < NCLS) out[b*NCLS + wl] = acc2;
}

extern "C" void kernel_launch(void* const* d_in, const int* in_sizes, int n_in,
                              void* d_out, int out_size, void* d_ws, size_t ws_size,
                              hipStream_t stream) {
    const float* x     = (const float*)d_in[0];
    const float* wts   = (const float*)d_in[1];
    const float* fc1_w = (const float*)d_in[2];
    const float* fc1_b = (const float*)d_in[3];
    const float* fc2_w = (const float*)d_in[4];
    const float* fc2_b = (const float*)d_in[5];
    float* out = (float*)d_out;

    const int B = in_sizes[0] / NQ;            // 16384
    const int grid = (B + EPB - 1) / EPB;      // 2048 blocks
    reupload_kernel<<<grid, 256, 0, stream>>>(x, wts, fc1_w, fc1_b, fc2_w, fc2_b, out, B);
}

// Round 10
// 28.067 us; speedup vs baseline: 1.3685x; 1.0694x over previous
//
#include <hip/hip_runtime.h>

constexpr int NQ = 7;
constexpr int NL = 4;
constexpr int NG = NL * NQ;   // 28
constexpr int NCLS = 22;
constexpr int EPB = 16;       // elements per 256-thread block (one per 16-lane group)

// ---------------- cross-lane primitives: R7/R9-PROVEN SET ----------------
// masks 1,2 -> DPP quad_perm; masks 4,8 -> ds_swizzle XOR. (R8 lesson: don't
// move shuffles onto the hot VALU pipe; R2/R3/R5 lesson: no inline-asm prims.)
template<int CTRL>
__device__ __forceinline__ float fdpp(float v) {
    return __int_as_float(__builtin_amdgcn_mov_dpp(__float_as_int(v), CTRL, 0xF, 0xF, true));
}
template<int OFF>
__device__ __forceinline__ float fswz(float v) {
    return __int_as_float(__builtin_amdgcn_ds_swizzle(__float_as_int(v), OFF));
}
template<int M>
__device__ __forceinline__ float xorl(float v) {
    if      constexpr (M == 1)  return fdpp<0xB1>(v);    // quad_perm [1,0,3,2]
    else if constexpr (M == 2)  return fdpp<0x4E>(v);    // quad_perm [2,3,0,1]
    else if constexpr (M == 4)  return fswz<0x101F>(v);  // xor4
    else                        return fswz<0x201F>(v);  // xor8
}

// ---------------- fused gate build: U' = U_rot @ RX(c,s) ----------------
__device__ __forceinline__ void fuse(const float* __restrict__ u, float c, float s,
                                     float4& A, float4& B) {
    A.x = fmaf(c, u[0],  s * u[3]);  A.y = fmaf(c, u[1], -s * u[2]);
    A.z = fmaf(c, u[2],  s * u[1]);  A.w = fmaf(c, u[3], -s * u[0]);
    B.x = fmaf(c, u[4],  s * u[7]);  B.y = fmaf(c, u[5], -s * u[6]);
    B.z = fmaf(c, u[6],  s * u[5]);  B.w = fmaf(c, u[7], -s * u[4]);
}

// 2x2 gate on a lane-bit qubit (pair across lane mask M), applied to 8 amps
template<int M>
__device__ __forceinline__ void gateL(int lane, float4 A, float4 B,
                                      float ar[8], float ai[8]) {
    const bool hi = (lane & M) != 0;
    const float avr = hi ? B.z : A.x, avi = hi ? B.w : A.y;   // diag coeff
    const float awr = hi ? B.x : A.z, awi = hi ? B.y : A.w;   // off-diag coeff
    #pragma unroll
    for (int k = 0; k < 8; ++k) {
        const float wr = xorl<M>(ar[k]), wi = xorl<M>(ai[k]);
        const float nr = avr*ar[k] - avi*ai[k] + awr*wr - awi*wi;
        const float ni = avr*ai[k] + avi*ar[k] + awr*wi + awi*wr;
        ar[k] = nr; ai[k] = ni;
    }
}

// full 2x2 on a register pair (v = row0 amp, w = row1 amp)
__device__ __forceinline__ void gate2(float4 A, float4 B,
                                      float& vr, float& vi, float& wr, float& wi) {
    const float n0r = A.x*vr - A.y*vi + A.z*wr - A.w*wi;
    const float n0i = A.x*vi + A.y*vr + A.z*wi + A.w*wr;
    const float n1r = B.x*vr - B.y*vi + B.z*wr - B.w*wi;
    const float n1i = B.x*vi + B.y*vr + B.z*wi + B.w*wr;
    vr = n0r; vi = n0i; wr = n1r; wi = n1i;
}

// CNOT with lane-bit target MT, lane-bit control MC, 8 amps
template<int MT, int MC>
__device__ __forceinline__ void cnotLT(int lane, float ar[8], float ai[8]) {
    const bool c = (lane & MC) != 0;
    #pragma unroll
    for (int k = 0; k < 8; ++k) {
        const float wr = xorl<MT>(ar[k]), wi = xorl<MT>(ai[k]);
        ar[k] = c ? wr : ar[k];
        ai[k] = c ? wi : ai[k];
    }
}

// ---------------- main kernel: FOUR elements per wave ----------------
// element = 16-lane group: grp = tid>>4 (0..15); in-group lane u = lane&15.
// amp index a = (u<<3)|k, bits a6..a0 = u3 u2 u1 u0 k2 k1 k0.
// qubit q <-> amp bit (6-q): q0->u3(m8) q1->u2(m4) q2->u1(m2) q3->u0(m1)
//                            q4->k2(local) q5->k1(local) q6->k0(local)
__global__ __launch_bounds__(256) void reupload_kernel(
    const float* __restrict__ x,       // (B,7)
    const float* __restrict__ wts,     // (4,7,3)
    const float* __restrict__ fc1_w,   // (32,7)
    const float* __restrict__ fc1_b,   // (32,)
    const float* __restrict__ fc2_w,   // (22,32)
    const float* __restrict__ fc2_b,   // (22,)
    float* __restrict__ out,           // (B,22)
    int B)
{
    __shared__ __align__(16) float rotU[NG * 8];        // 28 Rot matrices
    __shared__ float2 csb[EPB * NQ];                    // per-element RX (c,s)
    __shared__ __align__(16) float fU[NG * EPB * 8];    // fused matrices, 14 KiB
    __shared__ __align__(16) float hbuf[EPB][32];

    const int tid = threadIdx.x;
    // --- phase 0: c,s (112 thr) ∥ Rot matrices (28 thr on wave 2) ---
    if (tid < EPB * NQ) {
        const int e = tid / NQ, q = tid % NQ;
        const int bb = blockIdx.x * EPB + e;
        const float xv = (bb < B) ? x[bb*NQ + q] : 0.f;
        const float h = 0.5f * xv;
        csb[tid] = make_float2(__cosf(h), __sinf(h));
    } else if (tid >= 128 && tid < 128 + NG) {
        const int g = tid - 128;
        float phi = wts[g*3+0], th = wts[g*3+1], om = wts[g*3+2];
        float ct = __cosf(0.5f*th), st = __sinf(0.5f*th);
        float ap = 0.5f*(phi+om),  am = 0.5f*(phi-om);
        float cp = __cosf(ap), sp = __sinf(ap);
        float cm = __cosf(am), sm = __sinf(am);
        float* u = &rotU[g*8];
        u[0] =  cp*ct; u[1] = -sp*ct;   // u00 = ep*ct        (ep = cp - i sp)
        u[2] = -cm*st; u[3] = -sm*st;   // u01 = -conj(em)*st (em = cm - i sm)
        u[4] =  cm*st; u[5] = -sm*st;   // u10 = em*st
        u[6] =  cp*ct; u[7] =  sp*ct;   // u11 = conj(ep)*ct
    }
    __syncthreads();
    // --- phase 1: build fused matrices (448 = 2 per thread) ---
    #pragma unroll
    for (int i = tid; i < NG * EPB; i += 256) {
        const int g = i >> 4, e = i & 15;
        const int q = g % NQ;
        const float2 cs = csb[e*NQ + q];
        float4 A, Bq;
        fuse(&rotU[g*8], cs.x, cs.y, A, Bq);
        float4* dst = reinterpret_cast<float4*>(&fU[(g*EPB + e)*8]);
        dst[0] = A; dst[1] = Bq;
    }
    __syncthreads();

    const int lane = threadIdx.x & 63;
    const int u    = threadIdx.x & 15;          // in-group lane
    const int grp  = threadIdx.x >> 4;          // element slot in block (0..15)
    const int b    = blockIdx.x * EPB + grp;
    if (b >= B) return;

    // |0..0>: amp 0 at u=0,k=0
    float ar[8], ai[8];
    #pragma unroll
    for (int k = 0; k < 8; ++k) { ar[k] = 0.f; ai[k] = 0.f; }
    ar[0] = (u == 0) ? 1.f : 0.f;

    #pragma unroll
    for (int l = 0; l < NL; ++l) {
        float4 A, Bq;
        #define LOADU(q) { const float4* up = reinterpret_cast<const float4*>( \
            &fU[((l*NQ + (q))*EPB + grp)*8]); A = up[0]; Bq = up[1]; }
        LOADU(0); gateL<8>(lane, A, Bq, ar, ai);    // q0 -> u3
        LOADU(1); gateL<4>(lane, A, Bq, ar, ai);    // q1 -> u2
        LOADU(2); gateL<2>(lane, A, Bq, ar, ai);    // q2 -> u1
        LOADU(3); gateL<1>(lane, A, Bq, ar, ai);    // q3 -> u0
        LOADU(4);                                   // q4 -> k2: pairs (k, k+4)
        gate2(A, Bq, ar[0], ai[0], ar[4], ai[4]);
        gate2(A, Bq, ar[1], ai[1], ar[5], ai[5]);
        gate2(A, Bq, ar[2], ai[2], ar[6], ai[6]);
        gate2(A, Bq, ar[3], ai[3], ar[7], ai[7]);
        LOADU(5);                                   // q5 -> k1: pairs (k, k+2)
        gate2(A, Bq, ar[0], ai[0], ar[2], ai[2]);
        gate2(A, Bq, ar[1], ai[1], ar[3], ai[3]);
        gate2(A, Bq, ar[4], ai[4], ar[6], ai[6]);
        gate2(A, Bq, ar[5], ai[5], ar[7], ai[7]);
        LOADU(6);                                   // q6 -> k0: pairs (k, k+1)
        gate2(A, Bq, ar[0], ai[0], ar[1], ai[1]);
        gate2(A, Bq, ar[2], ai[2], ar[3], ai[3]);
        gate2(A, Bq, ar[4], ai[4], ar[5], ai[5]);
        gate2(A, Bq, ar[6], ai[6], ar[7], ai[7]);
        #undef LOADU

        // CNOT ring CNOT(q, q+1 mod 7), reference order q=0..6
        cnotLT<4,8>(lane, ar, ai);    // (0,1): ctrl u3, tgt u2
        cnotLT<2,4>(lane, ar, ai);    // (1,2): ctrl u2, tgt u1
        cnotLT<1,2>(lane, ar, ai);    // (2,3): ctrl u1, tgt u0
        {   // (3,4): ctrl u0 (lane&1), tgt k2 -> cond swap (k, k+4)
            const bool cc = (lane & 1) != 0;
            float t;
            #pragma unroll
            for (int k = 0; k < 4; ++k) {
                t = ar[k]; ar[k] = cc ? ar[k+4] : ar[k]; ar[k+4] = cc ? t : ar[k+4];
                t = ai[k]; ai[k] = cc ? ai[k+4] : ai[k]; ai[k+4] = cc ? t : ai[k+4];
            }
        }
        {   // (4,5): ctrl k2, tgt k1 -> amps 4..7 flip k1: 4<->6, 5<->7 (free)
            float t;
            t = ar[4]; ar[4] = ar[6]; ar[6] = t;
            t = ai[4]; ai[4] = ai[6]; ai[6] = t;
            t = ar[5]; ar[5] = ar[7]; ar[7] = t;
            t = ai[5]; ai[5] = ai[7]; ai[7] = t;
        }
        {   // (5,6): ctrl k1, tgt k0 -> amps k1=1 flip k0: 2<->3, 6<->7 (free)
            float t;
            t = ar[2]; ar[2] = ar[3]; ar[3] = t;
            t = ai[2]; ai[2] = ai[3]; ai[3] = t;
            t = ar[6]; ar[6] = ar[7]; ar[7] = t;
            t = ai[6]; ai[6] = ai[7]; ai[7] = t;
        }
        {   // (6,0): ctrl k0, tgt u3 -> odd amps swap across mask8 (uncond)
            ar[1] = xorl<8>(ar[1]); ai[1] = xorl<8>(ai[1]);
            ar[3] = xorl<8>(ar[3]); ai[3] = xorl<8>(ai[3]);
            ar[5] = xorl<8>(ar[5]); ai[5] = xorl<8>(ai[5]);
            ar[7] = xorl<8>(ar[7]); ai[7] = xorl<8>(ai[7]);
        }
    }

    // ---------- <Z_j> ----------
    float p[8];
    #pragma unroll
    for (int k = 0; k < 8; ++k) p[k] = ar[k]*ar[k] + ai[k]*ai[k];
    const float s04 = p[0]+p[1]+p[2]+p[3], s47 = p[4]+p[5]+p[6]+p[7];
    const float t = s04 + s47;
    float z[NQ];
    z[0] = (lane & 8) ? -t : t;
    z[1] = (lane & 4) ? -t : t;
    z[2] = (lane & 2) ? -t : t;
    z[3] = (lane & 1) ? -t : t;
    z[4] = s04 - s47;                                           // sign by k2
    z[5] = (p[0]+p[1]+p[4]+p[5]) - (p[2]+p[3]+p[6]+p[7]);       // sign by k1
    z[6] = (p[0]+p[2]+p[4]+p[6]) - (p[1]+p[3]+p[5]+p[7]);       // sign by k0
    #pragma unroll
    for (int j = 0; j < NQ; ++j) {
        float v = z[j];
        v += xorl<1>(v);
        v += xorl<2>(v);
        v += xorl<4>(v);
        v += xorl<8>(v);
        z[j] = v;   // per-element sum in every lane of the 16-group
    }

    // ---------- MLP 7 -> 32(relu) -> 22, per 16-lane group (2 rows/lane) ----------
    float acc1a = fc1_b[u], acc1b = fc1_b[u + 16];
    #pragma unroll
    for (int j = 0; j < NQ; ++j) {
        acc1a = fmaf(z[j], fc1_w[u*NQ + j], acc1a);
        acc1b = fmaf(z[j], fc1_w[(u+16)*NQ + j], acc1b);
    }
    hbuf[grp][u]      = fmaxf(acc1a, 0.f);
    hbuf[grp][u + 16] = fmaxf(acc1b, 0.f);
    __builtin_amdgcn_wave_barrier();
    asm volatile("s_waitcnt lgkmcnt(0)" ::: "memory");
    __builtin_amdgcn_sched_barrier(0);

    float hv[32];
    #pragma unroll
    for (int i = 0; i < 8; ++i) {   // broadcast reads within each group
        float4 v4 = *reinterpret_cast<const float4*>(&hbuf[grp][i*4]);
        hv[i*4+0] = v4.x; hv[i*4+1] = v4.y; hv[i*4+2] = v4.z; hv[i*4+3] = v4.w;
    }
    const int kb = (u < NCLS - 16) ? (u + 16) : 0;   // clamp row for u>=6
    float acc2a = fc2_b[u], acc2b = fc2_b[kb];
    const float4* w4a = reinterpret_cast<const float4*>(fc2_w + u*32);
    const float4* w4b = reinterpret_cast<const float4*>(fc2_w + kb*32);
    #pragma unroll
    for (int i = 0; i < 8; ++i) {
        float4 wa = w4a[i], wb = w4b[i];
        acc2a = fmaf(hv[i*4+0], wa.x, acc2a); acc2b = fmaf(hv[i*4+0], wb.x, acc2b);
        acc2a = fmaf(hv[i*4+1], wa.y, acc2a); acc2b = fmaf(hv[i*4+1], wb.y, acc2b);
        acc2a = fmaf(hv[i*4+2], wa.z, acc2a); acc2b = fmaf(hv[i*4+2], wb.z, acc2b);
        acc2a = fmaf(hv[i*4+3], wa.w, acc2a); acc2b = fmaf(hv[i*4+3], wb.w, acc2b);
    }
    out[b*NCLS + u] = acc2a;
    if (u < NCLS - 16) out[b*NCLS + 16 + u] = acc2b;

    (void)lane;
}

extern "C" void kernel_launch(void* const* d_in, const int* in_sizes, int n_in,
                              void* d_out, int out_size, void* d_ws, size_t ws_size,
                              hipStream_t stream) {
    const float* x     = (const float*)d_in[0];
    const float* wts   = (const float*)d_in[1];
    const float* fc1_w = (const float*)d_in[2];
    const float* fc1_b = (const float*)d_in[3];
    const float* fc2_w = (const float*)d_in[4];
    const float* fc2_b = (const float*)d_in[5];
    float* out = (float*)d_out;

    const int B = in_sizes[0] / NQ;            // 16384
    const int grid = (B + EPB - 1) / EPB;      // 1024 blocks
    reupload_kernel<<<grid, 256, 0, stream>>>(x, wts, fc1_w, fc1_b, fc2_w, fc2_b, out, B);
}

// Round 11
// 28.031 us; speedup vs baseline: 1.3702x; 1.0013x over previous
//
#include <hip/hip_runtime.h>

constexpr int NQ = 7;
constexpr int NL = 4;
constexpr int NG = NL * NQ;   // 28
constexpr int NCLS = 22;
constexpr int EPB = 16;       // elements per 256-thread block (one per 16-lane group)

// ---------------- cross-lane primitives: R7/R9/R10-PROVEN SET ----------------
// masks 1,2 -> DPP quad_perm; masks 4,8 -> ds_swizzle XOR; arbitrary gather ->
// __shfl (ds_bpermute, R1-proven). No inline-asm prims (R2/R3/R5 lesson).
template<int CTRL>
__device__ __forceinline__ float fdpp(float v) {
    return __int_as_float(__builtin_amdgcn_mov_dpp(__float_as_int(v), CTRL, 0xF, 0xF, true));
}
template<int OFF>
__device__ __forceinline__ float fswz(float v) {
    return __int_as_float(__builtin_amdgcn_ds_swizzle(__float_as_int(v), OFF));
}
template<int M>
__device__ __forceinline__ float xorl(float v) {
    if      constexpr (M == 1)  return fdpp<0xB1>(v);    // quad_perm [1,0,3,2]
    else if constexpr (M == 2)  return fdpp<0x4E>(v);    // quad_perm [2,3,0,1]
    else if constexpr (M == 4)  return fswz<0x101F>(v);  // xor4
    else                        return fswz<0x201F>(v);  // xor8
}

// ---------------- fused gate build: U' = U_rot @ RX(c,s) ----------------
__device__ __forceinline__ void fuse(const float* __restrict__ u, float c, float s,
                                     float4& A, float4& B) {
    A.x = fmaf(c, u[0],  s * u[3]);  A.y = fmaf(c, u[1], -s * u[2]);
    A.z = fmaf(c, u[2],  s * u[1]);  A.w = fmaf(c, u[3], -s * u[0]);
    B.x = fmaf(c, u[4],  s * u[7]);  B.y = fmaf(c, u[5], -s * u[6]);
    B.z = fmaf(c, u[6],  s * u[5]);  B.w = fmaf(c, u[7], -s * u[4]);
}

// 2x2 gate on a lane-bit qubit: batch-fetch all partners first (R11: lets the
// scheduler issue swizzles back-to-back and wait once), then the 64 FMAs.
template<int M>
__device__ __forceinline__ void gateL(int lane, float4 A, float4 B,
                                      float ar[8], float ai[8]) {
    const bool hi = (lane & M) != 0;
    const float avr = hi ? B.z : A.x, avi = hi ? B.w : A.y;   // diag coeff
    const float awr = hi ? B.x : A.z, awi = hi ? B.y : A.w;   // off-diag coeff
    float wr[8], wi[8];
    #pragma unroll
    for (int k = 0; k < 8; ++k) { wr[k] = xorl<M>(ar[k]); wi[k] = xorl<M>(ai[k]); }
    #pragma unroll
    for (int k = 0; k < 8; ++k) {
        const float nr = avr*ar[k] - avi*ai[k] + awr*wr[k] - awi*wi[k];
        const float ni = avr*ai[k] + avi*ar[k] + awr*wi[k] + awi*wr[k];
        ar[k] = nr; ai[k] = ni;
    }
}

// full 2x2 on a register pair (v = row0 amp, w = row1 amp)
__device__ __forceinline__ void gate2(float4 A, float4 B,
                                      float& vr, float& vi, float& wr, float& wi) {
    const float n0r = A.x*vr - A.y*vi + A.z*wr - A.w*wi;
    const float n0i = A.x*vi + A.y*vr + A.z*wi + A.w*wr;
    const float n1r = B.x*vr - B.y*vi + B.z*wr - B.w*wi;
    const float n1i = B.x*vi + B.y*vr + B.z*wi + B.w*wr;
    vr = n0r; vi = n0i; wr = n1r; wi = n1i;
}

// ---------------- main kernel: FOUR elements per wave ----------------
// element = 16-lane group: grp = tid>>4 (0..15); in-group lane u = lane&15.
// amp index a = (u<<3)|k, bits a6..a0 = u3 u2 u1 u0 k2 k1 k0.
// qubit q <-> amp bit (6-q): q0->u3(m8) q1->u2(m4) q2->u1(m2) q3->u0(m1)
//                            q4->k2(local) q5->k1(local) q6->k0(local)
__global__ __launch_bounds__(256) void reupload_kernel(
    const float* __restrict__ x,       // (B,7)
    const float* __restrict__ wts,     // (4,7,3)
    const float* __restrict__ fc1_w,   // (32,7)
    const float* __restrict__ fc1_b,   // (32,)
    const float* __restrict__ fc2_w,   // (22,32)
    const float* __restrict__ fc2_b,   // (22,)
    float* __restrict__ out,           // (B,22)
    int B)
{
    __shared__ __align__(16) float rotU[NG * 8];        // 28 Rot matrices
    __shared__ float2 csb[EPB * NQ];                    // per-element RX (c,s)
    __shared__ __align__(16) float fU[NG * EPB * 8];    // fused matrices, 14 KiB
    __shared__ __align__(16) float hbuf[EPB][32];

    const int tid = threadIdx.x;
    // --- phase 0: c,s (112 thr) ∥ Rot matrices (28 thr on wave 2) ---
    if (tid < EPB * NQ) {
        const int e = tid / NQ, q = tid % NQ;
        const int bb = blockIdx.x * EPB + e;
        const float xv = (bb < B) ? x[bb*NQ + q] : 0.f;
        const float h = 0.5f * xv;
        csb[tid] = make_float2(__cosf(h), __sinf(h));
    } else if (tid >= 128 && tid < 128 + NG) {
        const int g = tid - 128;
        float phi = wts[g*3+0], th = wts[g*3+1], om = wts[g*3+2];
        float ct = __cosf(0.5f*th), st = __sinf(0.5f*th);
        float ap = 0.5f*(phi+om),  am = 0.5f*(phi-om);
        float cp = __cosf(ap), sp = __sinf(ap);
        float cm = __cosf(am), sm = __sinf(am);
        float* u = &rotU[g*8];
        u[0] =  cp*ct; u[1] = -sp*ct;   // u00 = ep*ct        (ep = cp - i sp)
        u[2] = -cm*st; u[3] = -sm*st;   // u01 = -conj(em)*st (em = cm - i sm)
        u[4] =  cm*st; u[5] = -sm*st;   // u10 = em*st
        u[6] =  cp*ct; u[7] =  sp*ct;   // u11 = conj(ep)*ct
    }
    __syncthreads();
    // --- phase 1: build fused matrices (448 = 2 per thread) ---
    #pragma unroll
    for (int i = tid; i < NG * EPB; i += 256) {
        const int g = i >> 4, e = i & 15;
        const int q = g % NQ;
        const float2 cs = csb[e*NQ + q];
        float4 A, Bq;
        fuse(&rotU[g*8], cs.x, cs.y, A, Bq);
        float4* dst = reinterpret_cast<float4*>(&fU[(g*EPB + e)*8]);
        dst[0] = A; dst[1] = Bq;
    }
    __syncthreads();

    const int lane = threadIdx.x & 63;
    const int u    = threadIdx.x & 15;          // in-group lane
    const int grp  = threadIdx.x >> 4;          // element slot in block (0..15)
    const int b    = blockIdx.x * EPB + grp;
    if (b >= B) return;

    // merged CNOT(0,1)(1,2)(2,3) gather source: src_u = u ^ (u>>1) (in-group)
    const int srcLane = (lane & 48) | ((u ^ (u >> 1)) & 15);

    // |0..0>: amp 0 at u=0,k=0
    float ar[8], ai[8];
    #pragma unroll
    for (int k = 0; k < 8; ++k) { ar[k] = 0.f; ai[k] = 0.f; }
    ar[0] = (u == 0) ? 1.f : 0.f;

    #pragma unroll
    for (int l = 0; l < NL; ++l) {
        float4 A, Bq;
        #define LOADU(q) { const float4* up = reinterpret_cast<const float4*>( \
            &fU[((l*NQ + (q))*EPB + grp)*8]); A = up[0]; Bq = up[1]; }
        LOADU(0); gateL<8>(lane, A, Bq, ar, ai);    // q0 -> u3
        LOADU(1); gateL<4>(lane, A, Bq, ar, ai);    // q1 -> u2
        LOADU(2); gateL<2>(lane, A, Bq, ar, ai);    // q2 -> u1
        LOADU(3); gateL<1>(lane, A, Bq, ar, ai);    // q3 -> u0
        LOADU(4);                                   // q4 -> k2: pairs (k, k+4)
        gate2(A, Bq, ar[0], ai[0], ar[4], ai[4]);
        gate2(A, Bq, ar[1], ai[1], ar[5], ai[5]);
        gate2(A, Bq, ar[2], ai[2], ar[6], ai[6]);
        gate2(A, Bq, ar[3], ai[3], ar[7], ai[7]);
        LOADU(5);                                   // q5 -> k1: pairs (k, k+2)
        gate2(A, Bq, ar[0], ai[0], ar[2], ai[2]);
        gate2(A, Bq, ar[1], ai[1], ar[3], ai[3]);
        gate2(A, Bq, ar[4], ai[4], ar[6], ai[6]);
        gate2(A, Bq, ar[5], ai[5], ar[7], ai[7]);
        LOADU(6);                                   // q6 -> k0: pairs (k, k+1)
        gate2(A, Bq, ar[0], ai[0], ar[1], ai[1]);
        gate2(A, Bq, ar[2], ai[2], ar[3], ai[3]);
        gate2(A, Bq, ar[4], ai[4], ar[5], ai[5]);
        gate2(A, Bq, ar[6], ai[6], ar[7], ai[7]);
        #undef LOADU

        // --- CNOT ring CNOT(q, q+1 mod 7), reference order q=0..6 ---
        // (0,1)+(1,2)+(2,3) merged: new[u] = old[u ^ (u>>1)] — one gather
        #pragma unroll
        for (int k = 0; k < 8; ++k) {
            ar[k] = __shfl(ar[k], srcLane);
            ai[k] = __shfl(ai[k], srcLane);
        }
        {   // (3,4): ctrl u0 (lane&1), tgt k2 -> cond swap (k, k+4)
            const bool cc = (lane & 1) != 0;
            float t;
            #pragma unroll
            for (int k = 0; k < 4; ++k) {
                t = ar[k]; ar[k] = cc ? ar[k+4] : ar[k]; ar[k+4] = cc ? t : ar[k+4];
                t = ai[k]; ai[k] = cc ? ai[k+4] : ai[k]; ai[k+4] = cc ? t : ai[k+4];
            }
        }
        {   // (4,5): ctrl k2, tgt k1 -> amps 4..7 flip k1: 4<->6, 5<->7 (free)
            float t;
            t = ar[4]; ar[4] = ar[6]; ar[6] = t;
            t = ai[4]; ai[4] = ai[6]; ai[6] = t;
            t = ar[5]; ar[5] = ar[7]; ar[7] = t;
            t = ai[5]; ai[5] = ai[7]; ai[7] = t;
        }
        {   // (5,6): ctrl k1, tgt k0 -> amps k1=1 flip k0: 2<->3, 6<->7 (free)
            float t;
            t = ar[2]; ar[2] = ar[3]; ar[3] = t;
            t = ai[2]; ai[2] = ai[3]; ai[3] = t;
            t = ar[6]; ar[6] = ar[7]; ar[7] = t;
            t = ai[6]; ai[6] = ai[7]; ai[7] = t;
        }
        {   // (6,0): ctrl k0, tgt u3 -> odd amps swap across mask8 (uncond)
            ar[1] = xorl<8>(ar[1]); ai[1] = xorl<8>(ai[1]);
            ar[3] = xorl<8>(ar[3]); ai[3] = xorl<8>(ai[3]);
            ar[5] = xorl<8>(ar[5]); ai[5] = xorl<8>(ai[5]);
            ar[7] = xorl<8>(ar[7]); ai[7] = xorl<8>(ai[7]);
        }
    }

    // ---------- <Z_j> ----------
    float p[8];
    #pragma unroll
    for (int k = 0; k < 8; ++k) p[k] = ar[k]*ar[k] + ai[k]*ai[k];
    const float s04 = p[0]+p[1]+p[2]+p[3], s47 = p[4]+p[5]+p[6]+p[7];
    const float t = s04 + s47;
    float z[NQ];
    z[0] = (lane & 8) ? -t : t;
    z[1] = (lane & 4) ? -t : t;
    z[2] = (lane & 2) ? -t : t;
    z[3] = (lane & 1) ? -t : t;
    z[4] = s04 - s47;                                           // sign by k2
    z[5] = (p[0]+p[1]+p[4]+p[5]) - (p[2]+p[3]+p[6]+p[7]);       // sign by k1
    z[6] = (p[0]+p[2]+p[4]+p[6]) - (p[1]+p[3]+p[5]+p[7]);       // sign by k0
    #pragma unroll
    for (int j = 0; j < NQ; ++j) {
        float v = z[j];
        v += xorl<1>(v);
        v += xorl<2>(v);
        v += xorl<4>(v);
        v += xorl<8>(v);
        z[j] = v;   // per-element sum in every lane of the 16-group
    }

    // ---------- MLP 7 -> 32(relu) -> 22, per 16-lane group (2 rows/lane) ----------
    float acc1a = fc1_b[u], acc1b = fc1_b[u + 16];
    #pragma unroll
    for (int j = 0; j < NQ; ++j) {
        acc1a = fmaf(z[j], fc1_w[u*NQ + j], acc1a);
        acc1b = fmaf(z[j], fc1_w[(u+16)*NQ + j], acc1b);
    }
    hbuf[grp][u]      = fmaxf(acc1a, 0.f);
    hbuf[grp][u + 16] = fmaxf(acc1b, 0.f);
    __builtin_amdgcn_wave_barrier();
    asm volatile("s_waitcnt lgkmcnt(0)" ::: "memory");
    __builtin_amdgcn_sched_barrier(0);

    float hv[32];
    #pragma unroll
    for (int i = 0; i < 8; ++i) {   // broadcast reads within each group
        float4 v4 = *reinterpret_cast<const float4*>(&hbuf[grp][i*4]);
        hv[i*4+0] = v4.x; hv[i*4+1] = v4.y; hv[i*4+2] = v4.z; hv[i*4+3] = v4.w;
    }
    const int kb = (u < NCLS - 16) ? (u + 16) : 0;   // clamp row for u>=6
    float acc2a = fc2_b[u], acc2b = fc2_b[kb];
    const float4* w4a = reinterpret_cast<const float4*>(fc2_w + u*32);
    const float4* w4b = reinterpret_cast<const float4*>(fc2_w + kb*32);
    #pragma unroll
    for (int i = 0; i < 8; ++i) {
        float4 wa = w4a[i], wb = w4b[i];
        acc2a = fmaf(hv[i*4+0], wa.x, acc2a); acc2b = fmaf(hv[i*4+0], wb.x, acc2b);
        acc2a = fmaf(hv[i*4+1], wa.y, acc2a); acc2b = fmaf(hv[i*4+1], wb.y, acc2b);
        acc2a = fmaf(hv[i*4+2], wa.z, acc2a); acc2b = fmaf(hv[i*4+2], wb.z, acc2b);
        acc2a = fmaf(hv[i*4+3], wa.w, acc2a); acc2b = fmaf(hv[i*4+3], wb.w, acc2b);
    }
    out[b*NCLS + u] = acc2a;
    if (u < NCLS - 16) out[b*NCLS + 16 + u] = acc2b;
}

extern "C" void kernel_launch(void* const* d_in, const int* in_sizes, int n_in,
                              void* d_out, int out_size, void* d_ws, size_t ws_size,
                              hipStream_t stream) {
    const float* x     = (const float*)d_in[0];
    const float* wts   = (const float*)d_in[1];
    const float* fc1_w = (const float*)d_in[2];
    const float* fc1_b = (const float*)d_in[3];
    const float* fc2_w = (const float*)d_in[4];
    const float* fc2_b = (const float*)d_in[5];
    float* out = (float*)d_out;

    const int B = in_sizes[0] / NQ;            // 16384
    const int grid = (B + EPB - 1) / EPB;      // 1024 blocks
    reupload_kernel<<<grid, 256, 0, stream>>>(x, wts, fc1_w, fc1_b, fc2_w, fc2_b, out, B);
}

// Round 12
// 27.819 us; speedup vs baseline: 1.3807x; 1.0076x over previous
//
#include <hip/hip_runtime.h>

constexpr int NQ = 7;
constexpr int NL = 4;
constexpr int NG = NL * NQ;   // 28
constexpr int NCLS = 22;
constexpr int EPB = 16;       // elements per 256-thread block (one per 16-lane group)

// ---------------- cross-lane primitives ----------------
// masks 1,2 -> DPP quad_perm (proven R1..R11); mask 8 -> DPP ROW_ROR:8
// (0x128: (i+8)&15 == i^8, self-inverse so direction-safe; R8-proven on HW);
// mask 4 -> ds_swizzle xor4 (proven; no direction-safe DPP exists for xor4);
// gather -> __shfl/ds_bpermute (R1-proven). No inline-asm prims (R2/3/5 lesson).
template<int CTRL>
__device__ __forceinline__ float fdpp(float v) {
    return __int_as_float(__builtin_amdgcn_mov_dpp(__float_as_int(v), CTRL, 0xF, 0xF, true));
}
template<int OFF>
__device__ __forceinline__ float fswz(float v) {
    return __int_as_float(__builtin_amdgcn_ds_swizzle(__float_as_int(v), OFF));
}
template<int M>
__device__ __forceinline__ float xorl(float v) {
    if      constexpr (M == 1)  return fdpp<0xB1>(v);    // quad_perm [1,0,3,2]
    else if constexpr (M == 2)  return fdpp<0x4E>(v);    // quad_perm [2,3,0,1]
    else if constexpr (M == 4)  return fswz<0x101F>(v);  // ds_swizzle xor4
    else                        return fdpp<0x128>(v);   // ROW_ROR:8 == xor8 (R8-proven)
}

// ---------------- fused gate build: U' = U_rot @ RX(c,s) ----------------
__device__ __forceinline__ void fuse(const float* __restrict__ u, float c, float s,
                                     float4& A, float4& B) {
    A.x = fmaf(c, u[0],  s * u[3]);  A.y = fmaf(c, u[1], -s * u[2]);
    A.z = fmaf(c, u[2],  s * u[1]);  A.w = fmaf(c, u[3], -s * u[0]);
    B.x = fmaf(c, u[4],  s * u[7]);  B.y = fmaf(c, u[5], -s * u[6]);
    B.z = fmaf(c, u[6],  s * u[5]);  B.w = fmaf(c, u[7], -s * u[4]);
}

// 2x2 gate on a lane-bit qubit: batch-fetch partners, then the 64 FMAs.
template<int M>
__device__ __forceinline__ void gateL(int lane, float4 A, float4 B,
                                      float ar[8], float ai[8]) {
    const bool hi = (lane & M) != 0;
    const float avr = hi ? B.z : A.x, avi = hi ? B.w : A.y;   // diag coeff
    const float awr = hi ? B.x : A.z, awi = hi ? B.y : A.w;   // off-diag coeff
    float wr[8], wi[8];
    #pragma unroll
    for (int k = 0; k < 8; ++k) { wr[k] = xorl<M>(ar[k]); wi[k] = xorl<M>(ai[k]); }
    #pragma unroll
    for (int k = 0; k < 8; ++k) {
        const float nr = avr*ar[k] - avi*ai[k] + awr*wr[k] - awi*wi[k];
        const float ni = avr*ai[k] + avi*ar[k] + awr*wi[k] + awi*wr[k];
        ar[k] = nr; ai[k] = ni;
    }
}

// full 2x2 on a register pair (v = row0 amp, w = row1 amp)
__device__ __forceinline__ void gate2(float4 A, float4 B,
                                      float& vr, float& vi, float& wr, float& wi) {
    const float n0r = A.x*vr - A.y*vi + A.z*wr - A.w*wi;
    const float n0i = A.x*vi + A.y*vr + A.z*wi + A.w*wr;
    const float n1r = B.x*vr - B.y*vi + B.z*wr - B.w*wi;
    const float n1i = B.x*vi + B.y*vr + B.z*wi + B.w*wr;
    vr = n0r; vi = n0i; wr = n1r; wi = n1i;
}

// ---------------- main kernel: FOUR elements per wave ----------------
// element = 16-lane group: grp = tid>>4 (0..15); in-group lane u = lane&15.
// amp index a = (u<<3)|k, bits a6..a0 = u3 u2 u1 u0 k2 k1 k0.
// qubit q <-> amp bit (6-q): q0->u3(m8) q1->u2(m4) q2->u1(m2) q3->u0(m1)
//                            q4->k2(local) q5->k1(local) q6->k0(local)
__global__ __launch_bounds__(256) void reupload_kernel(
    const float* __restrict__ x,       // (B,7)
    const float* __restrict__ wts,     // (4,7,3)
    const float* __restrict__ fc1_w,   // (32,7)
    const float* __restrict__ fc1_b,   // (32,)
    const float* __restrict__ fc2_w,   // (22,32)
    const float* __restrict__ fc2_b,   // (22,)
    float* __restrict__ out,           // (B,22)
    int B)
{
    __shared__ __align__(16) float rotU[NG * 8];        // 28 Rot matrices
    __shared__ float2 csb[EPB * NQ];                    // per-element RX (c,s)
    __shared__ __align__(16) float fU[NG * EPB * 8];    // fused matrices, 14 KiB
    __shared__ __align__(16) float hbuf[EPB][32];

    const int tid = threadIdx.x;
    // --- phase 0: c,s (112 thr) ∥ Rot matrices (28 thr on wave 2) ---
    if (tid < EPB * NQ) {
        const int e = tid / NQ, q = tid % NQ;
        const int bb = blockIdx.x * EPB + e;
        const float xv = (bb < B) ? x[bb*NQ + q] : 0.f;
        const float h = 0.5f * xv;
        csb[tid] = make_float2(__cosf(h), __sinf(h));
    } else if (tid >= 128 && tid < 128 + NG) {
        const int g = tid - 128;
        float phi = wts[g*3+0], th = wts[g*3+1], om = wts[g*3+2];
        float ct = __cosf(0.5f*th), st = __sinf(0.5f*th);
        float ap = 0.5f*(phi+om),  am = 0.5f*(phi-om);
        float cp = __cosf(ap), sp = __sinf(ap);
        float cm = __cosf(am), sm = __sinf(am);
        float* u = &rotU[g*8];
        u[0] =  cp*ct; u[1] = -sp*ct;   // u00 = ep*ct        (ep = cp - i sp)
        u[2] = -cm*st; u[3] = -sm*st;   // u01 = -conj(em)*st (em = cm - i sm)
        u[4] =  cm*st; u[5] = -sm*st;   // u10 = em*st
        u[6] =  cp*ct; u[7] =  sp*ct;   // u11 = conj(ep)*ct
    }
    __syncthreads();
    // --- phase 1: build fused matrices (448 = 2 per thread) ---
    #pragma unroll
    for (int i = tid; i < NG * EPB; i += 256) {
        const int g = i >> 4, e = i & 15;
        const int q = g % NQ;
        const float2 cs = csb[e*NQ + q];
        float4 A, Bq;
        fuse(&rotU[g*8], cs.x, cs.y, A, Bq);
        float4* dst = reinterpret_cast<float4*>(&fU[(g*EPB + e)*8]);
        dst[0] = A; dst[1] = Bq;
    }
    __syncthreads();

    const int lane = threadIdx.x & 63;
    const int u    = threadIdx.x & 15;          // in-group lane
    const int grp  = threadIdx.x >> 4;          // element slot in block (0..15)
    const int b    = blockIdx.x * EPB + grp;
    if (b >= B) return;

    // merged CNOT(0,1)(1,2)(2,3) gather source: src_u = u ^ (u>>1) (in-group)
    const int srcLane = (lane & 48) | ((u ^ (u >> 1)) & 15);

    // |0..0>: amp 0 at u=0,k=0
    float ar[8], ai[8];
    #pragma unroll
    for (int k = 0; k < 8; ++k) { ar[k] = 0.f; ai[k] = 0.f; }
    ar[0] = (u == 0) ? 1.f : 0.f;

    #pragma unroll
    for (int l = 0; l < NL; ++l) {
        float4 A, Bq;
        #define LOADU(q) { const float4* up = reinterpret_cast<const float4*>( \
            &fU[((l*NQ + (q))*EPB + grp)*8]); A = up[0]; Bq = up[1]; }
        LOADU(0); gateL<8>(lane, A, Bq, ar, ai);    // q0 -> u3 (DPP now)
        LOADU(1); gateL<4>(lane, A, Bq, ar, ai);    // q1 -> u2 (DS swizzle)
        LOADU(2); gateL<2>(lane, A, Bq, ar, ai);    // q2 -> u1 (DPP)
        LOADU(3); gateL<1>(lane, A, Bq, ar, ai);    // q3 -> u0 (DPP)
        LOADU(4);                                   // q4 -> k2: pairs (k, k+4)
        gate2(A, Bq, ar[0], ai[0], ar[4], ai[4]);
        gate2(A, Bq, ar[1], ai[1], ar[5], ai[5]);
        gate2(A, Bq, ar[2], ai[2], ar[6], ai[6]);
        gate2(A, Bq, ar[3], ai[3], ar[7], ai[7]);
        LOADU(5);                                   // q5 -> k1: pairs (k, k+2)
        gate2(A, Bq, ar[0], ai[0], ar[2], ai[2]);
        gate2(A, Bq, ar[1], ai[1], ar[3], ai[3]);
        gate2(A, Bq, ar[4], ai[4], ar[6], ai[6]);
        gate2(A, Bq, ar[5], ai[5], ar[7], ai[7]);
        LOADU(6);                                   // q6 -> k0: pairs (k, k+1)
        gate2(A, Bq, ar[0], ai[0], ar[1], ai[1]);
        gate2(A, Bq, ar[2], ai[2], ar[3], ai[3]);
        gate2(A, Bq, ar[4], ai[4], ar[5], ai[5]);
        gate2(A, Bq, ar[6], ai[6], ar[7], ai[7]);
        #undef LOADU

        // --- CNOT ring CNOT(q, q+1 mod 7), reference order q=0..6 ---
        // (0,1)+(1,2)+(2,3) merged: new[u] = old[u ^ (u>>1)] — one gather
        #pragma unroll
        for (int k = 0; k < 8; ++k) {
            ar[k] = __shfl(ar[k], srcLane);
            ai[k] = __shfl(ai[k], srcLane);
        }
        {   // (3,4): ctrl u0 (lane&1), tgt k2 -> cond swap (k, k+4)
            const bool cc = (lane & 1) != 0;
            float t;
            #pragma unroll
            for (int k = 0; k < 4; ++k) {
                t = ar[k]; ar[k] = cc ? ar[k+4] : ar[k]; ar[k+4] = cc ? t : ar[k+4];
                t = ai[k]; ai[k] = cc ? ai[k+4] : ai[k]; ai[k+4] = cc ? t : ai[k+4];
            }
        }
        {   // (4,5): ctrl k2, tgt k1 -> amps 4..7 flip k1: 4<->6, 5<->7 (free)
            float t;
            t = ar[4]; ar[4] = ar[6]; ar[6] = t;
            t = ai[4]; ai[4] = ai[6]; ai[6] = t;
            t = ar[5]; ar[5] = ar[7]; ar[7] = t;
            t = ai[5]; ai[5] = ai[7]; ai[7] = t;
        }
        {   // (5,6): ctrl k1, tgt k0 -> amps k1=1 flip k0: 2<->3, 6<->7 (free)
            float t;
            t = ar[2]; ar[2] = ar[3]; ar[3] = t;
            t = ai[2]; ai[2] = ai[3]; ai[3] = t;
            t = ar[6]; ar[6] = ar[7]; ar[7] = t;
            t = ai[6]; ai[6] = ai[7]; ai[7] = t;
        }
        {   // (6,0): ctrl k0, tgt u3 -> odd amps swap across mask8 (DPP, uncond)
            ar[1] = xorl<8>(ar[1]); ai[1] = xorl<8>(ai[1]);
            ar[3] = xorl<8>(ar[3]); ai[3] = xorl<8>(ai[3]);
            ar[5] = xorl<8>(ar[5]); ai[5] = xorl<8>(ai[5]);
            ar[7] = xorl<8>(ar[7]); ai[7] = xorl<8>(ai[7]);
        }
    }

    // ---------- <Z_j> ----------
    float p[8];
    #pragma unroll
    for (int k = 0; k < 8; ++k) p[k] = ar[k]*ar[k] + ai[k]*ai[k];
    const float s04 = p[0]+p[1]+p[2]+p[3], s47 = p[4]+p[5]+p[6]+p[7];
    const float t = s04 + s47;
    float z[NQ];
    z[0] = (lane & 8) ? -t : t;
    z[1] = (lane & 4) ? -t : t;
    z[2] = (lane & 2) ? -t : t;
    z[3] = (lane & 1) ? -t : t;
    z[4] = s04 - s47;                                           // sign by k2
    z[5] = (p[0]+p[1]+p[4]+p[5]) - (p[2]+p[3]+p[6]+p[7]);       // sign by k1
    z[6] = (p[0]+p[2]+p[4]+p[6]) - (p[1]+p[3]+p[5]+p[7]);       // sign by k0
    // 16-lane reduction, all-DPP, direction-immune: after quad_perm stages v is
    // quad-uniform; total = v + ror8(v) + (ror4(v)+ror12(v)) — {ror4,ror12}
    // covers quads q±1 under either rotate-direction reading, ror8 self-inverse.
    #pragma unroll
    for (int j = 0; j < NQ; ++j) {
        float v = z[j];
        v += xorl<1>(v);
        v += xorl<2>(v);
        const float q4  = fdpp<0x124>(v);
        const float q8  = fdpp<0x128>(v);
        const float q12 = fdpp<0x12C>(v);
        z[j] = (v + q8) + (q4 + q12);   // per-element sum in every lane
    }

    // ---------- MLP 7 -> 32(relu) -> 22, per 16-lane group (2 rows/lane) ----------
    float acc1a = fc1_b[u], acc1b = fc1_b[u + 16];
    #pragma unroll
    for (int j = 0; j < NQ; ++j) {
        acc1a = fmaf(z[j], fc1_w[u*NQ + j], acc1a);
        acc1b = fmaf(z[j], fc1_w[(u+16)*NQ + j], acc1b);
    }
    hbuf[grp][u]      = fmaxf(acc1a, 0.f);
    hbuf[grp][u + 16] = fmaxf(acc1b, 0.f);
    __builtin_amdgcn_wave_barrier();
    asm volatile("s_waitcnt lgkmcnt(0)" ::: "memory");
    __builtin_amdgcn_sched_barrier(0);

    float hv[32];
    #pragma unroll
    for (int i = 0; i < 8; ++i) {   // broadcast reads within each group
        float4 v4 = *reinterpret_cast<const float4*>(&hbuf[grp][i*4]);
        hv[i*4+0] = v4.x; hv[i*4+1] = v4.y; hv[i*4+2] = v4.z; hv[i*4+3] = v4.w;
    }
    const int kb = (u < NCLS - 16) ? (u + 16) : 0;   // clamp row for u>=6
    float acc2a = fc2_b[u], acc2b = fc2_b[kb];
    const float4* w4a = reinterpret_cast<const float4*>(fc2_w + u*32);
    const float4* w4b = reinterpret_cast<const float4*>(fc2_w + kb*32);
    #pragma unroll
    for (int i = 0; i < 8; ++i) {
        float4 wa = w4a[i], wb = w4b[i];
        acc2a = fmaf(hv[i*4+0], wa.x, acc2a); acc2b = fmaf(hv[i*4+0], wb.x, acc2b);
        acc2a = fmaf(hv[i*4+1], wa.y, acc2a); acc2b = fmaf(hv[i*4+1], wb.y, acc2b);
        acc2a = fmaf(hv[i*4+2], wa.z, acc2a); acc2b = fmaf(hv[i*4+2], wb.z, acc2b);
        acc2a = fmaf(hv[i*4+3], wa.w, acc2a); acc2b = fmaf(hv[i*4+3], wb.w, acc2b);
    }
    out[b*NCLS + u] = acc2a;
    if (u < NCLS - 16) out[b*NCLS + 16 + u] = acc2b;
}

extern "C" void kernel_launch(void* const* d_in, const int* in_sizes, int n_in,
                              void* d_out, int out_size, void* d_ws, size_t ws_size,
                              hipStream_t stream) {
    const float* x     = (const float*)d_in[0];
    const float* wts   = (const float*)d_in[1];
    const float* fc1_w = (const float*)d_in[2];
    const float* fc1_b = (const float*)d_in[3];
    const float* fc2_w = (const float*)d_in[4];
    const float* fc2_b = (const float*)d_in[5];
    float* out = (float*)d_out;

    const int B = in_sizes[0] / NQ;            // 16384
    const int grid = (B + EPB - 1) / EPB;      // 1024 blocks
    reupload_kernel<<<grid, 256, 0, stream>>>(x, wts, fc1_w, fc1_b, fc2_w, fc2_b, out, B);
}